// Round 10
// baseline (2596.057 us; speedup 1.0000x reference)
//
#include <hip/hip_runtime.h>

typedef __bf16 bf16x8 __attribute__((ext_vector_type(8)));
typedef float f32x4 __attribute__((ext_vector_type(4)));
typedef unsigned short ushort8_t __attribute__((ext_vector_type(8)));
typedef unsigned short ushort4_t __attribute__((ext_vector_type(4)));

#define MFMA16(a, b, c) __builtin_amdgcn_mfma_f32_16x16x32_bf16((a), (b), (c), 0, 0, 0)

#define GLOAD16(gp, lp)                                                        \
  __builtin_amdgcn_global_load_lds(                                            \
      (__attribute__((address_space(1))) void*)(gp),                           \
      (__attribute__((address_space(3))) void*)(lp), 16, 0, 0)

#define WAITVM(N) asm volatile("s_waitcnt vmcnt(" #N ")" ::: "memory")
#define SCHEDFENCE __builtin_amdgcn_sched_barrier(0)

__device__ __forceinline__ unsigned short f2bf(float f) {
  unsigned u = __builtin_bit_cast(unsigned, f);
  return (unsigned short)((u + 0x7FFFu + ((u >> 16) & 1u)) >> 16);
}

// Tiled ("staging-order") layout for GEMM operands, [R][K] logical:
//   addr(r,k) = ((r>>4)*(K>>5) + (k>>5))*512 + ((k>>3)&3)*128 + (r&15)*8 + (k&7)
// One 16x32 tile = 512 contiguous elems = one GLOAD16; LDS linear; fragment
// ds_read_b128 at base + l*16B: conflict-free; staging fully coalesced.

// ---------------------------------------------------------------------------
__global__ __launch_bounds__(256) void transpose_f2b_tiled(
    const float* __restrict__ src, unsigned short* __restrict__ dst,
    int Kdim, int Ndim) {
  const long u = (long)blockIdx.x * 256 + threadIdx.x;  // 16B unit
  const long total = ((long)Kdim * Ndim) >> 3;
  if (u >= total) return;
  const int kt32 = Kdim >> 5;
  const long tile = u >> 6;
  const int t8 = (int)(u & 63);
  const int chunk = t8 >> 4, rowlow = t8 & 15;
  const int n = (int)(tile / kt32) * 16 + rowlow;
  const int k0 = (int)(tile % kt32) * 32 + chunk * 8;
  ushort8_t o;
#pragma unroll
  for (int e = 0; e < 8; e++) o[e] = f2bf(src[(long)(k0 + e) * Ndim + n]);
  *(ushort8_t*)(dst + (u << 3)) = o;
}

// ---------------------------------------------------------------------------
__global__ __launch_bounds__(256) void ln_kernel(
    const float* __restrict__ x, const float* __restrict__ gw,
    const float* __restrict__ gb, unsigned short* __restrict__ h) {
  const int row = blockIdx.x * 4 + (threadIdx.x >> 6);
  const int l = threadIdx.x & 63;
  const float* xr = x + (long)row * 768;
  f32x4 va[3];
#pragma unroll
  for (int i = 0; i < 3; i++) va[i] = *(const f32x4*)(xr + i * 256 + l * 4);
  float s = 0.f, ss = 0.f;
#pragma unroll
  for (int i = 0; i < 3; i++)
#pragma unroll
    for (int j = 0; j < 4; j++) {
      float t = va[i][j];
      s += t;
      ss += t * t;
    }
#pragma unroll
  for (int off = 1; off < 64; off <<= 1) {
    s += __shfl_xor(s, off, 64);
    ss += __shfl_xor(ss, off, 64);
  }
  const float mu = s * (1.f / 768.f);
  const float var = ss * (1.f / 768.f) - mu * mu;
  const float inv = rsqrtf(var + 1e-5f);
  const long tb = ((long)(row >> 4) * 24) << 9;
  const int rlow = (row & 15) * 8;
  const int coff = ((l >> 1) & 3) * 128 + rlow + (l & 1) * 4;
#pragma unroll
  for (int i = 0; i < 3; i++) {
    f32x4 wv = *(const f32x4*)(gw + i * 256 + l * 4);
    f32x4 bv = *(const f32x4*)(gb + i * 256 + l * 4);
    ushort4_t o;
#pragma unroll
    for (int j = 0; j < 4; j++) o[j] = f2bf((va[i][j] - mu) * inv * wv[j] + bv[j]);
    const long addr = tb + ((long)(i * 8 + (l >> 3)) << 9) + coff;
    *(ushort4_t*)(h + addr) = o;
  }
}

enum { EPI_QKV = 0, EPI_GELU = 1, EPI_RES = 2 };

// ---------------------------------------------------------------------------
// 256x256 pipelined GEMM (MLP1): 8 waves (2M x 4N, wave-tile 128x64), BK=64
// as two 32-k planes, tiled-linear LDS (conflict-free), 2 slots (128 KB).
// Counted-vmcnt schedule: per K-tile t:
//   WAITVM(8)  -- drains stage(t); stage(t+1)'s 8 loads stay IN FLIGHT
//   s_barrier  -- cross-wave visibility of stage(t)
//   compute(t) -- ds_read + MFMA (compiler lgkm waits; reads consumed by MFMA)
//   s_barrier  -- WAR: all waves done reading slot t&1
//   stage(t+2) -- overwrites slot t&1, safe by the barrier above
// stage(t) lands during compute(t-1) (~2500 cy >> load latency) so the
// counted wait is ~free; no vmcnt(0) drain in the main loop.
template <int EPI>
__global__ __launch_bounds__(512) void gemm256p(
    const unsigned short* __restrict__ A, const unsigned short* __restrict__ BT,
    int K, const float* __restrict__ bb0, unsigned short* __restrict__ o0) {
  __shared__ unsigned short As[2][2][8192];  // [slot][kk][16 grp x 512]
  __shared__ unsigned short Bs[2][2][8192];
  const int tid = threadIdx.x;
  const int w = tid >> 6, l = tid & 63;
  const int lr = l & 15, lg = l >> 4;
  const int wr = w >> 2, wc = w & 3;  // 2M x 4N (R6-validated mapping)

  // bijective XCD swizzle (nwg % 8 == 0)
  const int nx = gridDim.x;
  const int nwg = nx * gridDim.y;
  int wg = blockIdx.y * nx + blockIdx.x;
  {
    const int qq = nwg >> 3, rr = nwg & 7;
    const int xcd = wg & 7, idx = wg >> 3;
    wg = (xcd < rr ? xcd * (qq + 1) : rr * (qq + 1) + (xcd - rr) * qq) + idx;
  }
  const int bx = wg % nx, by = wg / nx;
  const int m0 = by * 256, n0 = bx * 256;

  const int nk32 = K >> 5;
  const long abase = (long)(m0 >> 4) * nk32;
  const long bbase = (long)(n0 >> 4) * nk32;

  // 8 gload_lds per wave per stage (A grp {w, w+8} + B grp {w, w+8}, 2 kk)
  auto stage = [&](int t) {
    const int slot = t & 1;
#pragma unroll
    for (int kk = 0; kk < 2; kk++) {
      const int pk = t * 2 + kk;
      GLOAD16(A + ((abase + (long)w * nk32 + pk) << 9) + l * 8,
              &As[slot][kk][w * 512 + l * 8]);
      GLOAD16(A + ((abase + (long)(w + 8) * nk32 + pk) << 9) + l * 8,
              &As[slot][kk][(w + 8) * 512 + l * 8]);
      GLOAD16(BT + ((bbase + (long)w * nk32 + pk) << 9) + l * 8,
              &Bs[slot][kk][w * 512 + l * 8]);
      GLOAD16(BT + ((bbase + (long)(w + 8) * nk32 + pk) << 9) + l * 8,
              &Bs[slot][kk][(w + 8) * 512 + l * 8]);
    }
  };

  f32x4 acc[8][4] = {};
  const int nk = K >> 6;  // >= 2
  stage(0);
  stage(1);
  for (int t = 0; t < nk; ++t) {
    const int slot = t & 1;
    if (t + 1 < nk) { WAITVM(8); } else { WAITVM(0); }
    SCHEDFENCE;
    __builtin_amdgcn_s_barrier();
    SCHEDFENCE;
#pragma unroll
    for (int kk = 0; kk < 2; kk++) {
      bf16x8 a[8], b[4];
#pragma unroll
      for (int i = 0; i < 8; i++)
        a[i] = *(const bf16x8*)(&As[slot][kk][(wr * 8 + i) * 512 + l * 8]);
#pragma unroll
      for (int j = 0; j < 4; j++)
        b[j] = *(const bf16x8*)(&Bs[slot][kk][(wc * 4 + j) * 512 + l * 8]);
      __builtin_amdgcn_s_setprio(1);
#pragma unroll
      for (int i = 0; i < 8; i++)
#pragma unroll
        for (int j = 0; j < 4; j++) acc[i][j] = MFMA16(a[i], b[j], acc[i][j]);
      __builtin_amdgcn_s_setprio(0);
    }
    SCHEDFENCE;
    __builtin_amdgcn_s_barrier();  // WAR guard before overwriting this slot
    SCHEDFENCE;
    if (t + 2 < nk) stage(t + 2);
  }

  // ----- epilogue (EPI_GELU; writes TILED gbuf, K=3072 -> 96 k-tiles) -----
#pragma unroll
  for (int fm = 0; fm < 8; fm++) {
    const int r = m0 + wr * 128 + fm * 16 + lg * 4;
#pragma unroll
    for (int fn = 0; fn < 4; fn++) {
      const int c = n0 + wc * 64 + fn * 16 + lr;
      const float bv = bb0[c];
      const long cpart = ((long)(c >> 5) << 9) + ((c >> 3) & 3) * 128 + (c & 7);
#pragma unroll
      for (int q = 0; q < 4; q++) {
        const int row = r + q;
        float v = acc[fm][fn][q] + bv;
        const float u = v * (0.7978845608f + 0.0356774081f * v * v);
        const float g = v / (1.0f + __expf(-2.0f * u));
        o0[(((long)(row >> 4) * 96) << 9) + cpart + (row & 15) * 8] = f2bf(g);
      }
    }
  }
}

// ---------------------------------------------------------------------------
// GEMM on TILED operands (R9-proven): tile BM x 128 (BM = MREP*32), 4 waves,
// BK=64 two-plane, 2-phase dbuf, one __syncthreads per K-step.
template <int EPI, int MREP>
__global__ __launch_bounds__(256) void gemm_bt(
    const unsigned short* __restrict__ A, const unsigned short* __restrict__ BT,
    int K, const float* __restrict__ bb0, const float* __restrict__ bb1,
    const float* __restrict__ bb2, unsigned short* __restrict__ o0,
    unsigned short* __restrict__ o1, unsigned short* __restrict__ o2,
    const float* oFin, float* oFout) {
  constexpr int BM = MREP * 32;
  constexpr int AG = BM / 16;  // A row-groups
  __shared__ unsigned short As[2][2][AG * 512];
  __shared__ unsigned short Bs[2][2][8 * 512];
  const int tid = threadIdx.x;
  const int w = tid >> 6, l = tid & 63;
  const int lr = l & 15, lg = l >> 4;
  const int wr = w >> 1, wc = w & 1;

  const int nx = gridDim.x;
  const int nwg = nx * gridDim.y;
  int wg = blockIdx.y * nx + blockIdx.x;
  {
    const int qq = nwg >> 3, rr = nwg & 7;
    const int xcd = wg & 7, idx = wg >> 3;
    wg = (xcd < rr ? xcd * (qq + 1) : rr * (qq + 1) + (xcd - rr) * qq) + idx;
  }
  const int bx = wg % nx, by = wg / nx;
  const int m0 = by * BM, n0 = bx * 128;

  const int nk32 = K >> 5;
  const long abase = (long)(m0 >> 4) * nk32;
  const long bbase = (long)(n0 >> 4) * nk32;

  auto stage = [&](int buf, int kt) {
#pragma unroll
    for (int kk = 0; kk < 2; kk++) {
      const int pk = kt * 2 + kk;
#pragma unroll
      for (int t = 0; t < AG / 4; t++) {
        const int g = w + t * 4;
        GLOAD16(A + ((abase + (long)g * nk32 + pk) << 9) + l * 8,
                &As[buf][kk][g * 512 + l * 8]);
      }
#pragma unroll
      for (int t = 0; t < 2; t++) {
        const int g = w + t * 4;
        GLOAD16(BT + ((bbase + (long)g * nk32 + pk) << 9) + l * 8,
                &Bs[buf][kk][g * 512 + l * 8]);
      }
    }
  };

  f32x4 acc[MREP][4] = {};
  const int nk = K >> 6;
  stage(0, 0);
  for (int kt = 0; kt < nk; ++kt) {
    const int cur = kt & 1;
    __syncthreads();  // drains stage(kt), issued one full compute-step ago
    if (kt + 1 < nk) stage(cur ^ 1, kt + 1);
#pragma unroll
    for (int kk = 0; kk < 2; kk++) {
      bf16x8 a[MREP], b[4];
#pragma unroll
      for (int i = 0; i < MREP; i++)
        a[i] = *(const bf16x8*)(&As[cur][kk][(wr * MREP + i) * 512 + l * 8]);
#pragma unroll
      for (int j = 0; j < 4; j++)
        b[j] = *(const bf16x8*)(&Bs[cur][kk][(wc * 4 + j) * 512 + l * 8]);
      __builtin_amdgcn_s_setprio(1);
#pragma unroll
      for (int i = 0; i < MREP; i++)
#pragma unroll
        for (int j = 0; j < 4; j++) acc[i][j] = MFMA16(a[i], b[j], acc[i][j]);
      __builtin_amdgcn_s_setprio(0);
    }
  }

  // ----- epilogue -----
  if (EPI == EPI_QKV) {
    const int whichq = n0 / 768;
    const int cc0 = n0 - whichq * 768;
    const float* bias = whichq == 0 ? bb0 : whichq == 1 ? bb1 : bb2;
    if (whichq < 2) {
      unsigned short* dst = whichq == 0 ? o0 : o1;
#pragma unroll
      for (int i = 0; i < MREP; i++) {
        const int r = m0 + wr * MREP * 16 + i * 16 + lg * 4;
#pragma unroll
        for (int j = 0; j < 4; j++) {
          const int ccol = cc0 + wc * 64 + j * 16 + lr;
          const int hd = ccol >> 6, d = ccol & 63;
          const float bv = bias[ccol];
#pragma unroll
          for (int q = 0; q < 4; q++) {
            const int row = r + q;
            const int bidx = row >> 9, n = row & 511;
            const long addr = ((long)(bidx * 12 + hd) * 512 + n) * 64 + d;
            dst[addr] = f2bf(acc[i][j][q] + bv);
          }
        }
      }
    } else {
#pragma unroll
      for (int i = 0; i < MREP; i++) {
        const int r = m0 + wr * MREP * 16 + i * 16 + lg * 4;
        const int bidx = r >> 9, nb = r & 511;
#pragma unroll
        for (int j = 0; j < 4; j++) {
          const int ccol = cc0 + wc * 64 + j * 16 + lr;
          const int hd = ccol >> 6, d = ccol & 63;
          const float bv = bias[ccol];
          ushort4_t pk;
#pragma unroll
          for (int q = 0; q < 4; q++) pk[q] = f2bf(acc[i][j][q] + bv);
          *(ushort4_t*)(&o2[((long)(bidx * 12 + hd) * 64 + d) * 512 + nb]) = pk;
        }
      }
    }
  } else if (EPI == EPI_GELU) {
#pragma unroll
    for (int i = 0; i < MREP; i++) {
      const int r = m0 + wr * MREP * 16 + i * 16 + lg * 4;
#pragma unroll
      for (int j = 0; j < 4; j++) {
        const int c = n0 + wc * 64 + j * 16 + lr;
        const float bv = bb0[c];
        const long cpart = ((long)(c >> 5) << 9) + ((c >> 3) & 3) * 128 + (c & 7);
#pragma unroll
        for (int q = 0; q < 4; q++) {
          const int row = r + q;
          float v = acc[i][j][q] + bv;
          const float u = v * (0.7978845608f + 0.0356774081f * v * v);
          const float g = v / (1.0f + __expf(-2.0f * u));
          o0[(((long)(row >> 4) * 96) << 9) + cpart + (row & 15) * 8] = f2bf(g);
        }
      }
    }
  } else {
#pragma unroll
    for (int i = 0; i < MREP; i++) {
      const int r = m0 + wr * MREP * 16 + i * 16 + lg * 4;
#pragma unroll
      for (int j = 0; j < 4; j++) {
        const int c = n0 + wc * 64 + j * 16 + lr;
        const float bv = bb0[c];
#pragma unroll
        for (int q = 0; q < 4; q++) {
          const long addr = (long)(r + q) * 768 + c;
          oFout[addr] = acc[i][j][q] + bv + oFin[addr];
        }
      }
    }
  }
}

// ---------------------------------------------------------------------------
// Flash attention (R7-proven, unchanged).
__global__ __launch_bounds__(256) void attn_kernel(
    const unsigned short* __restrict__ qg, const unsigned short* __restrict__ kg,
    const unsigned short* __restrict__ vtg, float* __restrict__ x) {
  __shared__ unsigned short Sh[128 * 64];
  __shared__ unsigned short Ks[2][64 * 64];
  __shared__ unsigned short Vt[2][64 * 64];
  const int qt = blockIdx.x, h = blockIdx.y, b = blockIdx.z;
  const int bh = b * 12 + h;
  const int tid = threadIdx.x, w = tid >> 6, l = tid & 63;
  const int lr = l & 15, lg = l >> 4;
  const int fchunk = ((l & 7) ^ ((l >> 3) & 7)) * 8;
  const int rk = lr & 7;

  const unsigned short* qbase =
      qg + ((long)bh * 512 + qt * 128 + w * 32 + (l >> 3)) * 64 + fchunk;
  unsigned short* shW = &Sh[w * 2048 + l * 8];
#pragma unroll
  for (int cc = 0; cc < 4; cc++) GLOAD16(qbase + cc * 8 * 64, shW + cc * 512);

  const unsigned short* kbase =
      kg + ((long)bh * 512 + w * 16 + (l >> 3)) * 64 + fchunk;
  const unsigned short* vbase =
      vtg + ((long)bh * 64 + w * 16 + (l >> 3)) * 512 + fchunk;
  unsigned short* KsW = &Ks[0][w * 1024 + l * 8];
  unsigned short* VtW = &Vt[0][w * 1024 + l * 8];

  auto stageKV = [&](int buf, int kt) {
#pragma unroll
    for (int cc = 0; cc < 2; cc++) {
      GLOAD16(kbase + (kt * 64 + cc * 8) * 64, KsW + buf * 4096 + cc * 512);
      GLOAD16(vbase + cc * 8 * 512 + kt * 64, VtW + buf * 4096 + cc * 512);
    }
  };
  stageKV(0, 0);
  __syncthreads();

  bf16x8 qa[2][2];
#pragma unroll
  for (int mi = 0; mi < 2; mi++)
#pragma unroll
    for (int ds = 0; ds < 2; ds++) {
      qa[mi][ds] = *(const bf16x8*)(&Sh[(w * 32 + mi * 16 + lr) * 64 +
                                        ((ds * 4 + lg) ^ rk) * 8]);
#pragma unroll
      for (int e = 0; e < 8; e++)
        qa[mi][ds][e] = (__bf16)(0.125f * (float)qa[mi][ds][e]);
    }

  unsigned short* Pw = &Sh[w * 2048];
  float lsum[8] = {};
  f32x4 o[2][4] = {};

  for (int kt = 0; kt < 8; ++kt) {
    const int cur = kt & 1;
    if (kt < 7) stageKV(cur ^ 1, kt + 1);

    f32x4 s[2][4] = {};
#pragma unroll
    for (int ds = 0; ds < 2; ++ds) {
      bf16x8 kb[4];
#pragma unroll
      for (int nj = 0; nj < 4; nj++)
        kb[nj] = *(const bf16x8*)(&Ks[cur][(nj * 16 + lr) * 64 +
                                           ((ds * 4 + lg) ^ rk) * 8]);
#pragma unroll
      for (int mi = 0; mi < 2; mi++)
#pragma unroll
        for (int nj = 0; nj < 4; nj++) s[mi][nj] = MFMA16(qa[mi][ds], kb[nj], s[mi][nj]);
    }

#pragma unroll
    for (int mi = 0; mi < 2; mi++)
#pragma unroll
      for (int nj = 0; nj < 4; nj++) {
        const int cL = nj * 2 + (lr >> 3);
#pragma unroll
        for (int q = 0; q < 4; q++) {
          const int row = mi * 16 + lg * 4 + q;
          const float p = __expf(s[mi][nj][q]);
          lsum[mi * 4 + q] += p;
          Pw[row * 64 + ((cL ^ (row & 7)) * 8) + (lr & 7)] = f2bf(p);
        }
      }

#pragma unroll
    for (int ks = 0; ks < 2; ++ks) {
      bf16x8 pa[2], vb[4];
#pragma unroll
      for (int mi = 0; mi < 2; mi++)
        pa[mi] = *(const bf16x8*)(&Pw[(mi * 16 + lr) * 64 +
                                      ((ks * 4 + lg) ^ rk) * 8]);
#pragma unroll
      for (int dj = 0; dj < 4; dj++)
        vb[dj] = *(const bf16x8*)(&Vt[cur][(dj * 16 + lr) * 64 +
                                           ((ks * 4 + lg) ^ rk) * 8]);
#pragma unroll
      for (int mi = 0; mi < 2; mi++)
#pragma unroll
        for (int dj = 0; dj < 4; dj++) o[mi][dj] = MFMA16(pa[mi], vb[dj], o[mi][dj]);
    }
    __syncthreads();
  }

#pragma unroll
  for (int i = 0; i < 8; i++) {
#pragma unroll
    for (int off = 1; off < 16; off <<= 1) lsum[i] += __shfl_xor(lsum[i], off, 64);
  }

#pragma unroll
  for (int mi = 0; mi < 2; mi++) {
#pragma unroll
    for (int q = 0; q < 4; q++) {
      const int n = qt * 128 + w * 32 + mi * 16 + lg * 4 + q;
      const float inv = 1.0f / lsum[mi * 4 + q];
      const long base = ((long)(b * 512 + n)) * 768 + h * 64;
#pragma unroll
      for (int dj = 0; dj < 4; dj++) {
        const long a = base + dj * 16 + lr;
        x[a] = x[a] + o[mi][dj][q] * inv;
      }
    }
  }
}

// ---------------------------------------------------------------------------
extern "C" void kernel_launch(void* const* d_in, const int* in_sizes, int n_in,
                              void* d_out, int out_size, void* d_ws,
                              size_t ws_size, hipStream_t stream) {
  const float* x_in = (const float*)d_in[0];
  const float* ln_w = (const float*)d_in[1];
  const float* ln_b = (const float*)d_in[2];
  const float* wq = (const float*)d_in[3];
  const float* bq = (const float*)d_in[4];
  const float* wk = (const float*)d_in[5];
  const float* bk = (const float*)d_in[6];
  const float* wv = (const float*)d_in[7];
  const float* bv = (const float*)d_in[8];
  const float* w1 = (const float*)d_in[9];
  const float* b1 = (const float*)d_in[10];
  const float* w2 = (const float*)d_in[11];
  const float* b2 = (const float*)d_in[12];

  char* p = (char*)d_ws;
  float* xw = (float*)p;            p += 8192L * 768 * 4;
  unsigned short* hbuf = (unsigned short*)p;  p += 8192L * 768 * 2;
  unsigned short* wqkvT = (unsigned short*)p; p += 2304L * 768 * 2;
  unsigned short* w1T = (unsigned short*)p;   p += 3072L * 768 * 2;
  unsigned short* w2T = (unsigned short*)p;   p += 768L * 3072 * 2;
  unsigned short* qb = (unsigned short*)p;
  unsigned short* kb = qb + 6291456L;
  unsigned short* vt = kb + 6291456L;
  unsigned short* gbuf = qb;  // MLP hidden reuses q/k/v region

  hipMemcpyAsync(xw, x_in, 8192L * 768 * 4, hipMemcpyDeviceToDevice, stream);

  transpose_f2b_tiled<<<(768 * 768 / 8 + 255) / 256, 256, 0, stream>>>(
      wq, wqkvT, 768, 768);
  transpose_f2b_tiled<<<(768 * 768 / 8 + 255) / 256, 256, 0, stream>>>(
      wk, wqkvT + 768L * 768, 768, 768);
  transpose_f2b_tiled<<<(768 * 768 / 8 + 255) / 256, 256, 0, stream>>>(
      wv, wqkvT + 2L * 768 * 768, 768, 768);
  transpose_f2b_tiled<<<(768 * 3072 / 8 + 255) / 256, 256, 0, stream>>>(
      w1, w1T, 768, 3072);
  transpose_f2b_tiled<<<(768 * 3072 / 8 + 255) / 256, 256, 0, stream>>>(
      w2, w2T, 3072, 768);

  for (int layer = 0; layer < 12; ++layer) {
    ln_kernel<<<2048, 256, 0, stream>>>(xw, ln_w, ln_b, hbuf);
    gemm_bt<EPI_QKV, 4><<<dim3(18, 64), 256, 0, stream>>>(
        hbuf, wqkvT, 768, bq, bk, bv, qb, kb, vt, nullptr, nullptr);
    attn_kernel<<<dim3(4, 12, 16), 256, 0, stream>>>(qb, kb, vt, xw);
    ln_kernel<<<2048, 256, 0, stream>>>(xw, ln_w, ln_b, hbuf);
    gemm256p<EPI_GELU><<<dim3(12, 32), 512, 0, stream>>>(
        hbuf, w1T, 768, b1, gbuf);
    gemm_bt<EPI_RES, 2><<<dim3(6, 128), 256, 0, stream>>>(
        gbuf, w2T, 3072, b2, nullptr, nullptr, nullptr, nullptr, nullptr, xw,
        layer == 11 ? (float*)d_out : xw);
  }
}

// Round 11
// 2544.246 us; speedup vs baseline: 1.0204x; 1.0204x over previous
//
#include <hip/hip_runtime.h>

typedef __bf16 bf16x8 __attribute__((ext_vector_type(8)));
typedef float f32x4 __attribute__((ext_vector_type(4)));
typedef unsigned short ushort8_t __attribute__((ext_vector_type(8)));
typedef unsigned short ushort4_t __attribute__((ext_vector_type(4)));

#define MFMA16(a, b, c) __builtin_amdgcn_mfma_f32_16x16x32_bf16((a), (b), (c), 0, 0, 0)

#define GLOAD16(gp, lp)                                                        \
  __builtin_amdgcn_global_load_lds(                                            \
      (__attribute__((address_space(1))) void*)(gp),                           \
      (__attribute__((address_space(3))) void*)(lp), 16, 0, 0)

#define WAITVM(N) asm volatile("s_waitcnt vmcnt(" #N ")" ::: "memory")
#define WAITLGKM asm volatile("s_waitcnt lgkmcnt(0)" ::: "memory")
#define SCHEDFENCE __builtin_amdgcn_sched_barrier(0)

__device__ __forceinline__ unsigned short f2bf(float f) {
  unsigned u = __builtin_bit_cast(unsigned, f);
  return (unsigned short)((u + 0x7FFFu + ((u >> 16) & 1u)) >> 16);
}

// Tiled ("staging-order") layout for GEMM operands, [R][K] logical:
//   addr(r,k) = ((r>>4)*(K>>5) + (k>>5))*512 + ((k>>3)&3)*128 + (r&15)*8 + (k&7)
// One 16x32 tile = 512 contiguous elems = one GLOAD16; LDS linear; fragment
// ds_read_b128 at base + l*16B: conflict-free; staging fully coalesced.

// ---------------------------------------------------------------------------
__global__ __launch_bounds__(256) void transpose_f2b_tiled(
    const float* __restrict__ src, unsigned short* __restrict__ dst,
    int Kdim, int Ndim) {
  const long u = (long)blockIdx.x * 256 + threadIdx.x;  // 16B unit
  const long total = ((long)Kdim * Ndim) >> 3;
  if (u >= total) return;
  const int kt32 = Kdim >> 5;
  const long tile = u >> 6;
  const int t8 = (int)(u & 63);
  const int chunk = t8 >> 4, rowlow = t8 & 15;
  const int n = (int)(tile / kt32) * 16 + rowlow;
  const int k0 = (int)(tile % kt32) * 32 + chunk * 8;
  ushort8_t o;
#pragma unroll
  for (int e = 0; e < 8; e++) o[e] = f2bf(src[(long)(k0 + e) * Ndim + n]);
  *(ushort8_t*)(dst + (u << 3)) = o;
}

// ---------------------------------------------------------------------------
__global__ __launch_bounds__(256) void ln_kernel(
    const float* __restrict__ x, const float* __restrict__ gw,
    const float* __restrict__ gb, unsigned short* __restrict__ h) {
  const int row = blockIdx.x * 4 + (threadIdx.x >> 6);
  const int l = threadIdx.x & 63;
  const float* xr = x + (long)row * 768;
  f32x4 va[3];
#pragma unroll
  for (int i = 0; i < 3; i++) va[i] = *(const f32x4*)(xr + i * 256 + l * 4);
  float s = 0.f, ss = 0.f;
#pragma unroll
  for (int i = 0; i < 3; i++)
#pragma unroll
    for (int j = 0; j < 4; j++) {
      float t = va[i][j];
      s += t;
      ss += t * t;
    }
#pragma unroll
  for (int off = 1; off < 64; off <<= 1) {
    s += __shfl_xor(s, off, 64);
    ss += __shfl_xor(ss, off, 64);
  }
  const float mu = s * (1.f / 768.f);
  const float var = ss * (1.f / 768.f) - mu * mu;
  const float inv = rsqrtf(var + 1e-5f);
  const long tb = ((long)(row >> 4) * 24) << 9;
  const int rlow = (row & 15) * 8;
  const int coff = ((l >> 1) & 3) * 128 + rlow + (l & 1) * 4;
#pragma unroll
  for (int i = 0; i < 3; i++) {
    f32x4 wv = *(const f32x4*)(gw + i * 256 + l * 4);
    f32x4 bv = *(const f32x4*)(gb + i * 256 + l * 4);
    ushort4_t o;
#pragma unroll
    for (int j = 0; j < 4; j++) o[j] = f2bf((va[i][j] - mu) * inv * wv[j] + bv[j]);
    const long addr = tb + ((long)(i * 8 + (l >> 3)) << 9) + coff;
    *(ushort4_t*)(h + addr) = o;
  }
}

enum { EPI_QKV = 0, EPI_GELU = 1, EPI_RES = 2 };

// ---------------------------------------------------------------------------
// MLP1: faithful m201-style 8-phase 256x256 GEMM. 8 waves (2M x 4N, wave-tile
// 128x64), BK=64. Staging unit = HALF-tile (128 rows x 64k = 16 KB, 2 gloads
// per thread); ring of 4 half-slots per operand (128 KB total LDS). Per
// K-tile: 4 phases (Gray-coded C-quadrants), each = {ds_read subtile, issue
// one half-tile prefetch, lgkmcnt(0), barrier, 16 MFMA in setprio(1)}.
// vmcnt(6) ONLY at tile starts (2 loads x 3 half-tiles in flight); never 0
// mid-loop. Epilogue: GELU -> tiled gbuf.
__global__ __launch_bounds__(512) void gemm256f(
    const unsigned short* __restrict__ A, const unsigned short* __restrict__ BT,
    int K, const float* __restrict__ bb0, unsigned short* __restrict__ o0) {
  __shared__ unsigned short Asl[4][16 * 512];  // 4 half-slots x 16 KB
  __shared__ unsigned short Bsl[4][16 * 512];
  const int tid = threadIdx.x;
  const int w = tid >> 6, l = tid & 63;
  const int lr = l & 15, lg = l >> 4;
  const int wr = w >> 2, wc = w & 3;

  // bijective XCD swizzle (nwg % 8 == 0)
  const int nx = gridDim.x;
  const int nwg = nx * gridDim.y;
  int wg = blockIdx.y * nx + blockIdx.x;
  {
    const int qq = nwg >> 3, rr = nwg & 7;
    const int xcd = wg & 7, idx = wg >> 3;
    wg = (xcd < rr ? xcd * (qq + 1) : rr * (qq + 1) + (xcd - rr) * qq) + idx;
  }
  const int bx = wg % nx, by = wg / nx;
  const int m0 = by * 256, n0 = bx * 256;

  const int nk32 = K >> 5;
  const long abase = (long)(m0 >> 4) * nk32;
  const long bbase = (long)(n0 >> 4) * nk32;

  // A-half (t,mh): row-groups {u*8 + mh*4 + i}; wave w stages u=w>>2, i=w&3.
  auto stageA = [&](int t, int mh) {
    const int slot = (2 * t + mh) & 3;
    const int G = (w >> 2) * 8 + mh * 4 + (w & 3);
    const int loff = ((w >> 2) * 8 + (w & 3) * 2) * 512;
#pragma unroll
    for (int kk = 0; kk < 2; kk++)
      GLOAD16(A + ((abase + (long)G * nk32 + t * 2 + kk) << 9) + l * 8,
              &Asl[slot][loff + kk * 512 + l * 8]);
  };
  // B-half (t,nh): col-groups {q*4 + nh*2 + j}; wave w stages q=w>>1, j=w&1.
  auto stageB = [&](int t, int nh) {
    const int slot = (2 * t + nh) & 3;
    const int G = (w >> 1) * 4 + nh * 2 + (w & 1);
    const int loff = (((w >> 1) * 2 + (w & 1)) * 2) * 512;
#pragma unroll
    for (int kk = 0; kk < 2; kk++)
      GLOAD16(BT + ((bbase + (long)G * nk32 + t * 2 + kk) << 9) + l * 8,
              &Bsl[slot][loff + kk * 512 + l * 8]);
  };

  f32x4 acc[8][4] = {};
  const int nk = K >> 6;  // 12 for K=768

  // prologue: T0 complete (A1 last), then T1.{A0,B0,B1} -> 14 loads in flight
  stageA(0, 0); stageB(0, 0); stageB(0, 1); stageA(0, 1);
  stageA(1, 0); stageB(1, 0); stageB(1, 1);

  for (int t = 0; t < nk; ++t) {
    const int sA0 = (2 * t) & 3, sA1 = (2 * t + 1) & 3;
    if (t < nk - 1) { WAITVM(6); } else { WAITVM(0); }
    SCHEDFENCE;
    __builtin_amdgcn_s_barrier();  // all waves' tile-t loads visible
    SCHEDFENCE;

    bf16x8 a[4][2], b0[2][2], b1[2][2];

    // ---- ph0: quadrant (m0,n0). reads A0(8)+B0(4); prefetch T(t+1).A1
#pragma unroll
    for (int f = 0; f < 4; f++)
#pragma unroll
      for (int kk = 0; kk < 2; kk++)
        a[f][kk] = *(const bf16x8*)&Asl[sA0][((wr * 4 + f) * 2 + kk) * 512 + l * 8];
#pragma unroll
    for (int g2 = 0; g2 < 2; g2++)
#pragma unroll
      for (int kk = 0; kk < 2; kk++)
        b0[g2][kk] = *(const bf16x8*)&Bsl[sA0][((wc * 2 + g2) * 2 + kk) * 512 + l * 8];
    if (t + 1 < nk) stageA(t + 1, 1);
    WAITLGKM; SCHEDFENCE;
    __builtin_amdgcn_s_barrier(); SCHEDFENCE;
    __builtin_amdgcn_s_setprio(1);
#pragma unroll
    for (int f = 0; f < 4; f++)
#pragma unroll
      for (int g2 = 0; g2 < 2; g2++)
#pragma unroll
        for (int kk = 0; kk < 2; kk++)
          acc[f][g2] = MFMA16(a[f][kk], b0[g2][kk], acc[f][g2]);
    __builtin_amdgcn_s_setprio(0);

    // ---- ph1: quadrant (m0,n1). reads B1(4); prefetch T(t+2).A0
#pragma unroll
    for (int g2 = 0; g2 < 2; g2++)
#pragma unroll
      for (int kk = 0; kk < 2; kk++)
        b1[g2][kk] = *(const bf16x8*)&Bsl[sA1][((wc * 2 + g2) * 2 + kk) * 512 + l * 8];
    if (t + 2 < nk) stageA(t + 2, 0);
    WAITLGKM; SCHEDFENCE;
    __builtin_amdgcn_s_barrier(); SCHEDFENCE;
    __builtin_amdgcn_s_setprio(1);
#pragma unroll
    for (int f = 0; f < 4; f++)
#pragma unroll
      for (int g2 = 0; g2 < 2; g2++)
#pragma unroll
        for (int kk = 0; kk < 2; kk++)
          acc[f][2 + g2] = MFMA16(a[f][kk], b1[g2][kk], acc[f][2 + g2]);
    __builtin_amdgcn_s_setprio(0);

    // ---- ph2: quadrant (m1,n1). reads A1(8); prefetch T(t+2).B0
#pragma unroll
    for (int f = 0; f < 4; f++)
#pragma unroll
      for (int kk = 0; kk < 2; kk++)
        a[f][kk] = *(const bf16x8*)&Asl[sA1][((wr * 4 + f) * 2 + kk) * 512 + l * 8];
    if (t + 2 < nk) stageB(t + 2, 0);
    WAITLGKM; SCHEDFENCE;
    __builtin_amdgcn_s_barrier(); SCHEDFENCE;
    __builtin_amdgcn_s_setprio(1);
#pragma unroll
    for (int f = 0; f < 4; f++)
#pragma unroll
      for (int g2 = 0; g2 < 2; g2++)
#pragma unroll
        for (int kk = 0; kk < 2; kk++)
          acc[4 + f][2 + g2] = MFMA16(a[f][kk], b1[g2][kk], acc[4 + f][2 + g2]);
    __builtin_amdgcn_s_setprio(0);

    // ---- ph3: quadrant (m1,n0). no reads (b0 held); prefetch T(t+2).B1
    if (t + 2 < nk) stageB(t + 2, 1);
    SCHEDFENCE;
    __builtin_amdgcn_s_barrier(); SCHEDFENCE;
    __builtin_amdgcn_s_setprio(1);
#pragma unroll
    for (int f = 0; f < 4; f++)
#pragma unroll
      for (int g2 = 0; g2 < 2; g2++)
#pragma unroll
        for (int kk = 0; kk < 2; kk++)
          acc[4 + f][g2] = MFMA16(a[f][kk], b0[g2][kk], acc[4 + f][g2]);
    __builtin_amdgcn_s_setprio(0);
  }

  // ----- epilogue: GELU -> tiled gbuf (K=3072 -> 96 k-tiles) -----
#pragma unroll
  for (int fm = 0; fm < 8; fm++) {
    const int r = m0 + wr * 128 + fm * 16 + lg * 4;
#pragma unroll
    for (int fn = 0; fn < 4; fn++) {
      const int c = n0 + wc * 64 + fn * 16 + lr;
      const float bv = bb0[c];
      const long cpart = ((long)(c >> 5) << 9) + ((c >> 3) & 3) * 128 + (c & 7);
#pragma unroll
      for (int q = 0; q < 4; q++) {
        const int row = r + q;
        float v = acc[fm][fn][q] + bv;
        const float u = v * (0.7978845608f + 0.0356774081f * v * v);
        const float g = v / (1.0f + __expf(-2.0f * u));
        o0[(((long)(row >> 4) * 96) << 9) + cpart + (row & 15) * 8] = f2bf(g);
      }
    }
  }
}

// ---------------------------------------------------------------------------
// GEMM on TILED operands (R9-proven): tile BM x 128 (BM = MREP*32), 4 waves,
// BK=64 two-plane, 2-phase dbuf, one __syncthreads per K-step.
template <int EPI, int MREP>
__global__ __launch_bounds__(256) void gemm_bt(
    const unsigned short* __restrict__ A, const unsigned short* __restrict__ BT,
    int K, const float* __restrict__ bb0, const float* __restrict__ bb1,
    const float* __restrict__ bb2, unsigned short* __restrict__ o0,
    unsigned short* __restrict__ o1, unsigned short* __restrict__ o2,
    const float* oFin, float* oFout) {
  constexpr int BM = MREP * 32;
  constexpr int AG = BM / 16;  // A row-groups
  __shared__ unsigned short As[2][2][AG * 512];
  __shared__ unsigned short Bs[2][2][8 * 512];
  const int tid = threadIdx.x;
  const int w = tid >> 6, l = tid & 63;
  const int lr = l & 15, lg = l >> 4;
  const int wr = w >> 1, wc = w & 1;

  const int nx = gridDim.x;
  const int nwg = nx * gridDim.y;
  int wg = blockIdx.y * nx + blockIdx.x;
  {
    const int qq = nwg >> 3, rr = nwg & 7;
    const int xcd = wg & 7, idx = wg >> 3;
    wg = (xcd < rr ? xcd * (qq + 1) : rr * (qq + 1) + (xcd - rr) * qq) + idx;
  }
  const int bx = wg % nx, by = wg / nx;
  const int m0 = by * BM, n0 = bx * 128;

  const int nk32 = K >> 5;
  const long abase = (long)(m0 >> 4) * nk32;
  const long bbase = (long)(n0 >> 4) * nk32;

  auto stage = [&](int buf, int kt) {
#pragma unroll
    for (int kk = 0; kk < 2; kk++) {
      const int pk = kt * 2 + kk;
#pragma unroll
      for (int t = 0; t < AG / 4; t++) {
        const int g = w + t * 4;
        GLOAD16(A + ((abase + (long)g * nk32 + pk) << 9) + l * 8,
                &As[buf][kk][g * 512 + l * 8]);
      }
#pragma unroll
      for (int t = 0; t < 2; t++) {
        const int g = w + t * 4;
        GLOAD16(BT + ((bbase + (long)g * nk32 + pk) << 9) + l * 8,
                &Bs[buf][kk][g * 512 + l * 8]);
      }
    }
  };

  f32x4 acc[MREP][4] = {};
  const int nk = K >> 6;
  stage(0, 0);
  for (int kt = 0; kt < nk; ++kt) {
    const int cur = kt & 1;
    __syncthreads();  // drains stage(kt), issued one full compute-step ago
    if (kt + 1 < nk) stage(cur ^ 1, kt + 1);
#pragma unroll
    for (int kk = 0; kk < 2; kk++) {
      bf16x8 a[MREP], b[4];
#pragma unroll
      for (int i = 0; i < MREP; i++)
        a[i] = *(const bf16x8*)(&As[cur][kk][(wr * MREP + i) * 512 + l * 8]);
#pragma unroll
      for (int j = 0; j < 4; j++)
        b[j] = *(const bf16x8*)(&Bs[cur][kk][(wc * 4 + j) * 512 + l * 8]);
      __builtin_amdgcn_s_setprio(1);
#pragma unroll
      for (int i = 0; i < MREP; i++)
#pragma unroll
        for (int j = 0; j < 4; j++) acc[i][j] = MFMA16(a[i], b[j], acc[i][j]);
      __builtin_amdgcn_s_setprio(0);
    }
  }

  // ----- epilogue -----
  if (EPI == EPI_QKV) {
    const int whichq = n0 / 768;
    const int cc0 = n0 - whichq * 768;
    const float* bias = whichq == 0 ? bb0 : whichq == 1 ? bb1 : bb2;
    if (whichq < 2) {
      unsigned short* dst = whichq == 0 ? o0 : o1;
#pragma unroll
      for (int i = 0; i < MREP; i++) {
        const int r = m0 + wr * MREP * 16 + i * 16 + lg * 4;
#pragma unroll
        for (int j = 0; j < 4; j++) {
          const int ccol = cc0 + wc * 64 + j * 16 + lr;
          const int hd = ccol >> 6, d = ccol & 63;
          const float bv = bias[ccol];
#pragma unroll
          for (int q = 0; q < 4; q++) {
            const int row = r + q;
            const int bidx = row >> 9, n = row & 511;
            const long addr = ((long)(bidx * 12 + hd) * 512 + n) * 64 + d;
            dst[addr] = f2bf(acc[i][j][q] + bv);
          }
        }
      }
    } else {
#pragma unroll
      for (int i = 0; i < MREP; i++) {
        const int r = m0 + wr * MREP * 16 + i * 16 + lg * 4;
        const int bidx = r >> 9, nb = r & 511;
#pragma unroll
        for (int j = 0; j < 4; j++) {
          const int ccol = cc0 + wc * 64 + j * 16 + lr;
          const int hd = ccol >> 6, d = ccol & 63;
          const float bv = bias[ccol];
          ushort4_t pk;
#pragma unroll
          for (int q = 0; q < 4; q++) pk[q] = f2bf(acc[i][j][q] + bv);
          *(ushort4_t*)(&o2[((long)(bidx * 12 + hd) * 64 + d) * 512 + nb]) = pk;
        }
      }
    }
  } else if (EPI == EPI_GELU) {
#pragma unroll
    for (int i = 0; i < MREP; i++) {
      const int r = m0 + wr * MREP * 16 + i * 16 + lg * 4;
#pragma unroll
      for (int j = 0; j < 4; j++) {
        const int c = n0 + wc * 64 + j * 16 + lr;
        const float bv = bb0[c];
        const long cpart = ((long)(c >> 5) << 9) + ((c >> 3) & 3) * 128 + (c & 7);
#pragma unroll
        for (int q = 0; q < 4; q++) {
          const int row = r + q;
          float v = acc[i][j][q] + bv;
          const float u = v * (0.7978845608f + 0.0356774081f * v * v);
          const float g = v / (1.0f + __expf(-2.0f * u));
          o0[(((long)(row >> 4) * 96) << 9) + cpart + (row & 15) * 8] = f2bf(g);
        }
      }
    }
  } else {
#pragma unroll
    for (int i = 0; i < MREP; i++) {
      const int r = m0 + wr * MREP * 16 + i * 16 + lg * 4;
#pragma unroll
      for (int j = 0; j < 4; j++) {
        const int c = n0 + wc * 64 + j * 16 + lr;
        const float bv = bb0[c];
#pragma unroll
        for (int q = 0; q < 4; q++) {
          const long addr = (long)(r + q) * 768 + c;
          oFout[addr] = acc[i][j][q] + bv + oFin[addr];
        }
      }
    }
  }
}

// ---------------------------------------------------------------------------
// Flash attention (R7-proven, unchanged).
__global__ __launch_bounds__(256) void attn_kernel(
    const unsigned short* __restrict__ qg, const unsigned short* __restrict__ kg,
    const unsigned short* __restrict__ vtg, float* __restrict__ x) {
  __shared__ unsigned short Sh[128 * 64];
  __shared__ unsigned short Ks[2][64 * 64];
  __shared__ unsigned short Vt[2][64 * 64];
  const int qt = blockIdx.x, h = blockIdx.y, b = blockIdx.z;
  const int bh = b * 12 + h;
  const int tid = threadIdx.x, w = tid >> 6, l = tid & 63;
  const int lr = l & 15, lg = l >> 4;
  const int fchunk = ((l & 7) ^ ((l >> 3) & 7)) * 8;
  const int rk = lr & 7;

  const unsigned short* qbase =
      qg + ((long)bh * 512 + qt * 128 + w * 32 + (l >> 3)) * 64 + fchunk;
  unsigned short* shW = &Sh[w * 2048 + l * 8];
#pragma unroll
  for (int cc = 0; cc < 4; cc++) GLOAD16(qbase + cc * 8 * 64, shW + cc * 512);

  const unsigned short* kbase =
      kg + ((long)bh * 512 + w * 16 + (l >> 3)) * 64 + fchunk;
  const unsigned short* vbase =
      vtg + ((long)bh * 64 + w * 16 + (l >> 3)) * 512 + fchunk;
  unsigned short* KsW = &Ks[0][w * 1024 + l * 8];
  unsigned short* VtW = &Vt[0][w * 1024 + l * 8];

  auto stageKV = [&](int buf, int kt) {
#pragma unroll
    for (int cc = 0; cc < 2; cc++) {
      GLOAD16(kbase + (kt * 64 + cc * 8) * 64, KsW + buf * 4096 + cc * 512);
      GLOAD16(vbase + cc * 8 * 512 + kt * 64, VtW + buf * 4096 + cc * 512);
    }
  };
  stageKV(0, 0);
  __syncthreads();

  bf16x8 qa[2][2];
#pragma unroll
  for (int mi = 0; mi < 2; mi++)
#pragma unroll
    for (int ds = 0; ds < 2; ds++) {
      qa[mi][ds] = *(const bf16x8*)(&Sh[(w * 32 + mi * 16 + lr) * 64 +
                                        ((ds * 4 + lg) ^ rk) * 8]);
#pragma unroll
      for (int e = 0; e < 8; e++)
        qa[mi][ds][e] = (__bf16)(0.125f * (float)qa[mi][ds][e]);
    }

  unsigned short* Pw = &Sh[w * 2048];
  float lsum[8] = {};
  f32x4 o[2][4] = {};

  for (int kt = 0; kt < 8; ++kt) {
    const int cur = kt & 1;
    if (kt < 7) stageKV(cur ^ 1, kt + 1);

    f32x4 s[2][4] = {};
#pragma unroll
    for (int ds = 0; ds < 2; ++ds) {
      bf16x8 kb[4];
#pragma unroll
      for (int nj = 0; nj < 4; nj++)
        kb[nj] = *(const bf16x8*)(&Ks[cur][(nj * 16 + lr) * 64 +
                                           ((ds * 4 + lg) ^ rk) * 8]);
#pragma unroll
      for (int mi = 0; mi < 2; mi++)
#pragma unroll
        for (int nj = 0; nj < 4; nj++) s[mi][nj] = MFMA16(qa[mi][ds], kb[nj], s[mi][nj]);
    }

#pragma unroll
    for (int mi = 0; mi < 2; mi++)
#pragma unroll
      for (int nj = 0; nj < 4; nj++) {
        const int cL = nj * 2 + (lr >> 3);
#pragma unroll
        for (int q = 0; q < 4; q++) {
          const int row = mi * 16 + lg * 4 + q;
          const float p = __expf(s[mi][nj][q]);
          lsum[mi * 4 + q] += p;
          Pw[row * 64 + ((cL ^ (row & 7)) * 8) + (lr & 7)] = f2bf(p);
        }
      }

#pragma unroll
    for (int ks = 0; ks < 2; ++ks) {
      bf16x8 pa[2], vb[4];
#pragma unroll
      for (int mi = 0; mi < 2; mi++)
        pa[mi] = *(const bf16x8*)(&Pw[(mi * 16 + lr) * 64 +
                                      ((ks * 4 + lg) ^ rk) * 8]);
#pragma unroll
      for (int dj = 0; dj < 4; dj++)
        vb[dj] = *(const bf16x8*)(&Vt[cur][(dj * 16 + lr) * 64 +
                                           ((ks * 4 + lg) ^ rk) * 8]);
#pragma unroll
      for (int mi = 0; mi < 2; mi++)
#pragma unroll
        for (int dj = 0; dj < 4; dj++) o[mi][dj] = MFMA16(pa[mi], vb[dj], o[mi][dj]);
    }
    __syncthreads();
  }

#pragma unroll
  for (int i = 0; i < 8; i++) {
#pragma unroll
    for (int off = 1; off < 16; off <<= 1) lsum[i] += __shfl_xor(lsum[i], off, 64);
  }

#pragma unroll
  for (int mi = 0; mi < 2; mi++) {
#pragma unroll
    for (int q = 0; q < 4; q++) {
      const int n = qt * 128 + w * 32 + mi * 16 + lg * 4 + q;
      const float inv = 1.0f / lsum[mi * 4 + q];
      const long base = ((long)(b * 512 + n)) * 768 + h * 64;
#pragma unroll
      for (int dj = 0; dj < 4; dj++) {
        const long a = base + dj * 16 + lr;
        x[a] = x[a] + o[mi][dj][q] * inv;
      }
    }
  }
}

// ---------------------------------------------------------------------------
extern "C" void kernel_launch(void* const* d_in, const int* in_sizes, int n_in,
                              void* d_out, int out_size, void* d_ws,
                              size_t ws_size, hipStream_t stream) {
  const float* x_in = (const float*)d_in[0];
  const float* ln_w = (const float*)d_in[1];
  const float* ln_b = (const float*)d_in[2];
  const float* wq = (const float*)d_in[3];
  const float* bq = (const float*)d_in[4];
  const float* wk = (const float*)d_in[5];
  const float* bk = (const float*)d_in[6];
  const float* wv = (const float*)d_in[7];
  const float* bv = (const float*)d_in[8];
  const float* w1 = (const float*)d_in[9];
  const float* b1 = (const float*)d_in[10];
  const float* w2 = (const float*)d_in[11];
  const float* b2 = (const float*)d_in[12];

  char* p = (char*)d_ws;
  float* xw = (float*)p;            p += 8192L * 768 * 4;
  unsigned short* hbuf = (unsigned short*)p;  p += 8192L * 768 * 2;
  unsigned short* wqkvT = (unsigned short*)p; p += 2304L * 768 * 2;
  unsigned short* w1T = (unsigned short*)p;   p += 3072L * 768 * 2;
  unsigned short* w2T = (unsigned short*)p;   p += 768L * 3072 * 2;
  unsigned short* qb = (unsigned short*)p;
  unsigned short* kb = qb + 6291456L;
  unsigned short* vt = kb + 6291456L;
  unsigned short* gbuf = qb;  // MLP hidden reuses q/k/v region

  hipMemcpyAsync(xw, x_in, 8192L * 768 * 4, hipMemcpyDeviceToDevice, stream);

  transpose_f2b_tiled<<<(768 * 768 / 8 + 255) / 256, 256, 0, stream>>>(
      wq, wqkvT, 768, 768);
  transpose_f2b_tiled<<<(768 * 768 / 8 + 255) / 256, 256, 0, stream>>>(
      wk, wqkvT + 768L * 768, 768, 768);
  transpose_f2b_tiled<<<(768 * 768 / 8 + 255) / 256, 256, 0, stream>>>(
      wv, wqkvT + 2L * 768 * 768, 768, 768);
  transpose_f2b_tiled<<<(768 * 3072 / 8 + 255) / 256, 256, 0, stream>>>(
      w1, w1T, 768, 3072);
  transpose_f2b_tiled<<<(768 * 3072 / 8 + 255) / 256, 256, 0, stream>>>(
      w2, w2T, 3072, 768);

  for (int layer = 0; layer < 12; ++layer) {
    ln_kernel<<<2048, 256, 0, stream>>>(xw, ln_w, ln_b, hbuf);
    gemm_bt<EPI_QKV, 4><<<dim3(18, 64), 256, 0, stream>>>(
        hbuf, wqkvT, 768, bq, bk, bv, qb, kb, vt, nullptr, nullptr);
    attn_kernel<<<dim3(4, 12, 16), 256, 0, stream>>>(qb, kb, vt, xw);
    ln_kernel<<<2048, 256, 0, stream>>>(xw, ln_w, ln_b, hbuf);
    gemm256f<<<dim3(12, 32), 512, 0, stream>>>(hbuf, w1T, 768, b1, gbuf);
    gemm_bt<EPI_RES, 2><<<dim3(6, 128), 256, 0, stream>>>(
        gbuf, w2T, 3072, b2, nullptr, nullptr, nullptr, nullptr, nullptr, xw,
        layer == 11 ? (float*)d_out : xw);
  }
}

// Round 12
// 2540.707 us; speedup vs baseline: 1.0218x; 1.0014x over previous
//
#include <hip/hip_runtime.h>

typedef __bf16 bf16x8 __attribute__((ext_vector_type(8)));
typedef float f32x4 __attribute__((ext_vector_type(4)));
typedef unsigned short ushort8_t __attribute__((ext_vector_type(8)));
typedef unsigned short ushort4_t __attribute__((ext_vector_type(4)));

#define MFMA16(a, b, c) __builtin_amdgcn_mfma_f32_16x16x32_bf16((a), (b), (c), 0, 0, 0)

#define GLOAD16(gp, lp)                                                        \
  __builtin_amdgcn_global_load_lds(                                            \
      (__attribute__((address_space(1))) void*)(gp),                           \
      (__attribute__((address_space(3))) void*)(lp), 16, 0, 0)

__device__ __forceinline__ unsigned short f2bf(float f) {
  unsigned u = __builtin_bit_cast(unsigned, f);
  return (unsigned short)((u + 0x7FFFu + ((u >> 16) & 1u)) >> 16);
}

// Tiled ("staging-order") layout for GEMM operands, [R][K] logical:
//   addr(r,k) = ((r>>4)*(K>>5) + (k>>5))*512 + ((k>>3)&3)*128 + (r&15)*8 + (k&7)
// One 16x32 tile = 512 contiguous elems = one GLOAD16; LDS linear; fragment
// ds_read_b128 at base + l*16B: conflict-free; staging fully coalesced.

// ---------------------------------------------------------------------------
__global__ __launch_bounds__(256) void transpose_f2b_tiled(
    const float* __restrict__ src, unsigned short* __restrict__ dst,
    int Kdim, int Ndim) {
  const long u = (long)blockIdx.x * 256 + threadIdx.x;  // 16B unit
  const long total = ((long)Kdim * Ndim) >> 3;
  if (u >= total) return;
  const int kt32 = Kdim >> 5;
  const long tile = u >> 6;
  const int t8 = (int)(u & 63);
  const int chunk = t8 >> 4, rowlow = t8 & 15;
  const int n = (int)(tile / kt32) * 16 + rowlow;
  const int k0 = (int)(tile % kt32) * 32 + chunk * 8;
  ushort8_t o;
#pragma unroll
  for (int e = 0; e < 8; e++) o[e] = f2bf(src[(long)(k0 + e) * Ndim + n]);
  *(ushort8_t*)(dst + (u << 3)) = o;
}

// ---------------------------------------------------------------------------
__global__ __launch_bounds__(256) void ln_kernel(
    const float* __restrict__ x, const float* __restrict__ gw,
    const float* __restrict__ gb, unsigned short* __restrict__ h) {
  const int row = blockIdx.x * 4 + (threadIdx.x >> 6);
  const int l = threadIdx.x & 63;
  const float* xr = x + (long)row * 768;
  f32x4 va[3];
#pragma unroll
  for (int i = 0; i < 3; i++) va[i] = *(const f32x4*)(xr + i * 256 + l * 4);
  float s = 0.f, ss = 0.f;
#pragma unroll
  for (int i = 0; i < 3; i++)
#pragma unroll
    for (int j = 0; j < 4; j++) {
      float t = va[i][j];
      s += t;
      ss += t * t;
    }
#pragma unroll
  for (int off = 1; off < 64; off <<= 1) {
    s += __shfl_xor(s, off, 64);
    ss += __shfl_xor(ss, off, 64);
  }
  const float mu = s * (1.f / 768.f);
  const float var = ss * (1.f / 768.f) - mu * mu;
  const float inv = rsqrtf(var + 1e-5f);
  const long tb = ((long)(row >> 4) * 24) << 9;
  const int rlow = (row & 15) * 8;
  const int coff = ((l >> 1) & 3) * 128 + rlow + (l & 1) * 4;
#pragma unroll
  for (int i = 0; i < 3; i++) {
    f32x4 wv = *(const f32x4*)(gw + i * 256 + l * 4);
    f32x4 bv = *(const f32x4*)(gb + i * 256 + l * 4);
    ushort4_t o;
#pragma unroll
    for (int j = 0; j < 4; j++) o[j] = f2bf((va[i][j] - mu) * inv * wv[j] + bv[j]);
    const long addr = tb + ((long)(i * 8 + (l >> 3)) << 9) + coff;
    *(ushort4_t*)(h + addr) = o;
  }
}

enum { EPI_QKV = 0, EPI_GELU = 1, EPI_RES = 2 };

// ---------------------------------------------------------------------------
// GEMM on TILED operands (R9-proven): tile BM x 128 (BM = MREP*32), 4 waves,
// BK=64 two-plane, 2-phase dbuf, one __syncthreads per K-step.
template <int EPI, int MREP>
__global__ __launch_bounds__(256) void gemm_bt(
    const unsigned short* __restrict__ A, const unsigned short* __restrict__ BT,
    int K, const float* __restrict__ bb0, const float* __restrict__ bb1,
    const float* __restrict__ bb2, unsigned short* __restrict__ o0,
    unsigned short* __restrict__ o1, unsigned short* __restrict__ o2,
    const float* oFin, float* oFout) {
  constexpr int BM = MREP * 32;
  constexpr int AG = BM / 16;  // A row-groups
  __shared__ unsigned short As[2][2][AG * 512];
  __shared__ unsigned short Bs[2][2][8 * 512];
  const int tid = threadIdx.x;
  const int w = tid >> 6, l = tid & 63;
  const int lr = l & 15, lg = l >> 4;
  const int wr = w >> 1, wc = w & 1;

  const int nx = gridDim.x;
  const int nwg = nx * gridDim.y;
  int wg = blockIdx.y * nx + blockIdx.x;
  {
    const int qq = nwg >> 3, rr = nwg & 7;
    const int xcd = wg & 7, idx = wg >> 3;
    wg = (xcd < rr ? xcd * (qq + 1) : rr * (qq + 1) + (xcd - rr) * qq) + idx;
  }
  const int bx = wg % nx, by = wg / nx;
  const int m0 = by * BM, n0 = bx * 128;

  const int nk32 = K >> 5;
  const long abase = (long)(m0 >> 4) * nk32;
  const long bbase = (long)(n0 >> 4) * nk32;

  auto stage = [&](int buf, int kt) {
#pragma unroll
    for (int kk = 0; kk < 2; kk++) {
      const int pk = kt * 2 + kk;
#pragma unroll
      for (int t = 0; t < AG / 4; t++) {
        const int g = w + t * 4;
        GLOAD16(A + ((abase + (long)g * nk32 + pk) << 9) + l * 8,
                &As[buf][kk][g * 512 + l * 8]);
      }
#pragma unroll
      for (int t = 0; t < 2; t++) {
        const int g = w + t * 4;
        GLOAD16(BT + ((bbase + (long)g * nk32 + pk) << 9) + l * 8,
                &Bs[buf][kk][g * 512 + l * 8]);
      }
    }
  };

  f32x4 acc[MREP][4] = {};
  const int nk = K >> 6;
  stage(0, 0);
  for (int kt = 0; kt < nk; ++kt) {
    const int cur = kt & 1;
    __syncthreads();  // drains stage(kt), issued one full compute-step ago
    if (kt + 1 < nk) stage(cur ^ 1, kt + 1);
#pragma unroll
    for (int kk = 0; kk < 2; kk++) {
      bf16x8 a[MREP], b[4];
#pragma unroll
      for (int i = 0; i < MREP; i++)
        a[i] = *(const bf16x8*)(&As[cur][kk][(wr * MREP + i) * 512 + l * 8]);
#pragma unroll
      for (int j = 0; j < 4; j++)
        b[j] = *(const bf16x8*)(&Bs[cur][kk][(wc * 4 + j) * 512 + l * 8]);
      __builtin_amdgcn_s_setprio(1);
#pragma unroll
      for (int i = 0; i < MREP; i++)
#pragma unroll
        for (int j = 0; j < 4; j++) acc[i][j] = MFMA16(a[i], b[j], acc[i][j]);
      __builtin_amdgcn_s_setprio(0);
    }
  }

  // ----- epilogue -----
  if (EPI == EPI_QKV) {
    const int whichq = n0 / 768;
    const int cc0 = n0 - whichq * 768;
    const float* bias = whichq == 0 ? bb0 : whichq == 1 ? bb1 : bb2;
    if (whichq < 2) {
      unsigned short* dst = whichq == 0 ? o0 : o1;
#pragma unroll
      for (int i = 0; i < MREP; i++) {
        const int r = m0 + wr * MREP * 16 + i * 16 + lg * 4;
#pragma unroll
        for (int j = 0; j < 4; j++) {
          const int ccol = cc0 + wc * 64 + j * 16 + lr;
          const int hd = ccol >> 6, d = ccol & 63;
          const float bv = bias[ccol];
#pragma unroll
          for (int q = 0; q < 4; q++) {
            const int row = r + q;
            const int bidx = row >> 9, n = row & 511;
            const long addr = ((long)(bidx * 12 + hd) * 512 + n) * 64 + d;
            dst[addr] = f2bf(acc[i][j][q] + bv);
          }
        }
      }
    } else {
#pragma unroll
      for (int i = 0; i < MREP; i++) {
        const int r = m0 + wr * MREP * 16 + i * 16 + lg * 4;
        const int bidx = r >> 9, nb = r & 511;
#pragma unroll
        for (int j = 0; j < 4; j++) {
          const int ccol = cc0 + wc * 64 + j * 16 + lr;
          const int hd = ccol >> 6, d = ccol & 63;
          const float bv = bias[ccol];
          ushort4_t pk;
#pragma unroll
          for (int q = 0; q < 4; q++) pk[q] = f2bf(acc[i][j][q] + bv);
          *(ushort4_t*)(&o2[((long)(bidx * 12 + hd) * 64 + d) * 512 + nb]) = pk;
        }
      }
    }
  } else if (EPI == EPI_GELU) {
#pragma unroll
    for (int i = 0; i < MREP; i++) {
      const int r = m0 + wr * MREP * 16 + i * 16 + lg * 4;
#pragma unroll
      for (int j = 0; j < 4; j++) {
        const int c = n0 + wc * 64 + j * 16 + lr;
        const float bv = bb0[c];
        const long cpart = ((long)(c >> 5) << 9) + ((c >> 3) & 3) * 128 + (c & 7);
#pragma unroll
        for (int q = 0; q < 4; q++) {
          const int row = r + q;
          float v = acc[i][j][q] + bv;
          const float u = v * (0.7978845608f + 0.0356774081f * v * v);
          const float g = v / (1.0f + __expf(-2.0f * u));
          o0[(((long)(row >> 4) * 96) << 9) + cpart + (row & 15) * 8] = f2bf(g);
        }
      }
    }
  } else {
#pragma unroll
    for (int i = 0; i < MREP; i++) {
      const int r = m0 + wr * MREP * 16 + i * 16 + lg * 4;
#pragma unroll
      for (int j = 0; j < 4; j++) {
        const int c = n0 + wc * 64 + j * 16 + lr;
        const float bv = bb0[c];
#pragma unroll
        for (int q = 0; q < 4; q++) {
          const long addr = (long)(r + q) * 768 + c;
          oFout[addr] = acc[i][j][q] + bv + oFin[addr];
        }
      }
    }
  }
}

// ---------------------------------------------------------------------------
// Flash attention (R7-proven, unchanged).
__global__ __launch_bounds__(256) void attn_kernel(
    const unsigned short* __restrict__ qg, const unsigned short* __restrict__ kg,
    const unsigned short* __restrict__ vtg, float* __restrict__ x) {
  __shared__ unsigned short Sh[128 * 64];
  __shared__ unsigned short Ks[2][64 * 64];
  __shared__ unsigned short Vt[2][64 * 64];
  const int qt = blockIdx.x, h = blockIdx.y, b = blockIdx.z;
  const int bh = b * 12 + h;
  const int tid = threadIdx.x, w = tid >> 6, l = tid & 63;
  const int lr = l & 15, lg = l >> 4;
  const int fchunk = ((l & 7) ^ ((l >> 3) & 7)) * 8;
  const int rk = lr & 7;

  const unsigned short* qbase =
      qg + ((long)bh * 512 + qt * 128 + w * 32 + (l >> 3)) * 64 + fchunk;
  unsigned short* shW = &Sh[w * 2048 + l * 8];
#pragma unroll
  for (int cc = 0; cc < 4; cc++) GLOAD16(qbase + cc * 8 * 64, shW + cc * 512);

  const unsigned short* kbase =
      kg + ((long)bh * 512 + w * 16 + (l >> 3)) * 64 + fchunk;
  const unsigned short* vbase =
      vtg + ((long)bh * 64 + w * 16 + (l >> 3)) * 512 + fchunk;
  unsigned short* KsW = &Ks[0][w * 1024 + l * 8];
  unsigned short* VtW = &Vt[0][w * 1024 + l * 8];

  auto stageKV = [&](int buf, int kt) {
#pragma unroll
    for (int cc = 0; cc < 2; cc++) {
      GLOAD16(kbase + (kt * 64 + cc * 8) * 64, KsW + buf * 4096 + cc * 512);
      GLOAD16(vbase + cc * 8 * 512 + kt * 64, VtW + buf * 4096 + cc * 512);
    }
  };
  stageKV(0, 0);
  __syncthreads();

  bf16x8 qa[2][2];
#pragma unroll
  for (int mi = 0; mi < 2; mi++)
#pragma unroll
    for (int ds = 0; ds < 2; ds++) {
      qa[mi][ds] = *(const bf16x8*)(&Sh[(w * 32 + mi * 16 + lr) * 64 +
                                        ((ds * 4 + lg) ^ rk) * 8]);
#pragma unroll
      for (int e = 0; e < 8; e++)
        qa[mi][ds][e] = (__bf16)(0.125f * (float)qa[mi][ds][e]);
    }

  unsigned short* Pw = &Sh[w * 2048];
  float lsum[8] = {};
  f32x4 o[2][4] = {};

  for (int kt = 0; kt < 8; ++kt) {
    const int cur = kt & 1;
    if (kt < 7) stageKV(cur ^ 1, kt + 1);

    f32x4 s[2][4] = {};
#pragma unroll
    for (int ds = 0; ds < 2; ++ds) {
      bf16x8 kb[4];
#pragma unroll
      for (int nj = 0; nj < 4; nj++)
        kb[nj] = *(const bf16x8*)(&Ks[cur][(nj * 16 + lr) * 64 +
                                           ((ds * 4 + lg) ^ rk) * 8]);
#pragma unroll
      for (int mi = 0; mi < 2; mi++)
#pragma unroll
        for (int nj = 0; nj < 4; nj++) s[mi][nj] = MFMA16(qa[mi][ds], kb[nj], s[mi][nj]);
    }

#pragma unroll
    for (int mi = 0; mi < 2; mi++)
#pragma unroll
      for (int nj = 0; nj < 4; nj++) {
        const int cL = nj * 2 + (lr >> 3);
#pragma unroll
        for (int q = 0; q < 4; q++) {
          const int row = mi * 16 + lg * 4 + q;
          const float p = __expf(s[mi][nj][q]);
          lsum[mi * 4 + q] += p;
          Pw[row * 64 + ((cL ^ (row & 7)) * 8) + (lr & 7)] = f2bf(p);
        }
      }

#pragma unroll
    for (int ks = 0; ks < 2; ++ks) {
      bf16x8 pa[2], vb[4];
#pragma unroll
      for (int mi = 0; mi < 2; mi++)
        pa[mi] = *(const bf16x8*)(&Pw[(mi * 16 + lr) * 64 +
                                      ((ks * 4 + lg) ^ rk) * 8]);
#pragma unroll
      for (int dj = 0; dj < 4; dj++)
        vb[dj] = *(const bf16x8*)(&Vt[cur][(dj * 16 + lr) * 64 +
                                           ((ks * 4 + lg) ^ rk) * 8]);
#pragma unroll
      for (int mi = 0; mi < 2; mi++)
#pragma unroll
        for (int dj = 0; dj < 4; dj++) o[mi][dj] = MFMA16(pa[mi], vb[dj], o[mi][dj]);
    }
    __syncthreads();
  }

#pragma unroll
  for (int i = 0; i < 8; i++) {
#pragma unroll
    for (int off = 1; off < 16; off <<= 1) lsum[i] += __shfl_xor(lsum[i], off, 64);
  }

#pragma unroll
  for (int mi = 0; mi < 2; mi++) {
#pragma unroll
    for (int q = 0; q < 4; q++) {
      const int n = qt * 128 + w * 32 + mi * 16 + lg * 4 + q;
      const float inv = 1.0f / lsum[mi * 4 + q];
      const long base = ((long)(b * 512 + n)) * 768 + h * 64;
#pragma unroll
      for (int dj = 0; dj < 4; dj++) {
        const long a = base + dj * 16 + lr;
        x[a] = x[a] + o[mi][dj][q] * inv;
      }
    }
  }
}

// ---------------------------------------------------------------------------
extern "C" void kernel_launch(void* const* d_in, const int* in_sizes, int n_in,
                              void* d_out, int out_size, void* d_ws,
                              size_t ws_size, hipStream_t stream) {
  const float* x_in = (const float*)d_in[0];
  const float* ln_w = (const float*)d_in[1];
  const float* ln_b = (const float*)d_in[2];
  const float* wq = (const float*)d_in[3];
  const float* bq = (const float*)d_in[4];
  const float* wk = (const float*)d_in[5];
  const float* bk = (const float*)d_in[6];
  const float* wv = (const float*)d_in[7];
  const float* bv = (const float*)d_in[8];
  const float* w1 = (const float*)d_in[9];
  const float* b1 = (const float*)d_in[10];
  const float* w2 = (const float*)d_in[11];
  const float* b2 = (const float*)d_in[12];

  char* p = (char*)d_ws;
  float* xw = (float*)p;            p += 8192L * 768 * 4;
  unsigned short* hbuf = (unsigned short*)p;  p += 8192L * 768 * 2;
  unsigned short* wqkvT = (unsigned short*)p; p += 2304L * 768 * 2;
  unsigned short* w1T = (unsigned short*)p;   p += 3072L * 768 * 2;
  unsigned short* w2T = (unsigned short*)p;   p += 768L * 3072 * 2;
  unsigned short* qb = (unsigned short*)p;
  unsigned short* kb = qb + 6291456L;
  unsigned short* vt = kb + 6291456L;
  unsigned short* gbuf = qb;  // MLP hidden reuses q/k/v region

  hipMemcpyAsync(xw, x_in, 8192L * 768 * 4, hipMemcpyDeviceToDevice, stream);

  transpose_f2b_tiled<<<(768 * 768 / 8 + 255) / 256, 256, 0, stream>>>(
      wq, wqkvT, 768, 768);
  transpose_f2b_tiled<<<(768 * 768 / 8 + 255) / 256, 256, 0, stream>>>(
      wk, wqkvT + 768L * 768, 768, 768);
  transpose_f2b_tiled<<<(768 * 768 / 8 + 255) / 256, 256, 0, stream>>>(
      wv, wqkvT + 2L * 768 * 768, 768, 768);
  transpose_f2b_tiled<<<(768 * 3072 / 8 + 255) / 256, 256, 0, stream>>>(
      w1, w1T, 768, 3072);
  transpose_f2b_tiled<<<(768 * 3072 / 8 + 255) / 256, 256, 0, stream>>>(
      w2, w2T, 3072, 768);

  for (int layer = 0; layer < 12; ++layer) {
    ln_kernel<<<2048, 256, 0, stream>>>(xw, ln_w, ln_b, hbuf);
    gemm_bt<EPI_QKV, 4><<<dim3(18, 64), 256, 0, stream>>>(
        hbuf, wqkvT, 768, bq, bk, bv, qb, kb, vt, nullptr, nullptr);
    attn_kernel<<<dim3(4, 12, 16), 256, 0, stream>>>(qb, kb, vt, xw);
    ln_kernel<<<2048, 256, 0, stream>>>(xw, ln_w, ln_b, hbuf);
    // MLP1 in MLP2's proven geometry: BM=64, 3 blocks/CU, 4 perfect rounds
    gemm_bt<EPI_GELU, 2><<<dim3(24, 128), 256, 0, stream>>>(
        hbuf, w1T, 768, b1, nullptr, nullptr, gbuf, nullptr, nullptr, nullptr,
        nullptr);
    gemm_bt<EPI_RES, 2><<<dim3(6, 128), 256, 0, stream>>>(
        gbuf, w2T, 3072, b2, nullptr, nullptr, nullptr, nullptr, nullptr, xw,
        layer == 11 ? (float*)d_out : xw);
  }
}